// Round 5
// baseline (213.535 us; speedup 1.0000x reference)
//
#include <hip/hip_runtime.h>

typedef unsigned short ushort_t;
typedef __attribute__((ext_vector_type(8))) short short8;
typedef __attribute__((ext_vector_type(4))) float f32x4;

#define DIMC 512
#define PN   32768                  // 8*64*64 spatial positions
#define SQRTC 22.627416997969522f   // sqrt(512)

__device__ __forceinline__ ushort_t f2bf(float f) {
  unsigned int u = __float_as_uint(f);
  unsigned int r = u + 0x7fffu + ((u >> 16) & 1u);   // round-to-nearest-even
  return (ushort_t)(r >> 16);
}

// swizzle key: spreads 8 values over 16 consecutive rows AND over stride-4 rows
__device__ __forceinline__ int kkey(int r) { return (r & 7) ^ ((r >> 2) & 7); }

__device__ __forceinline__ uint4 pack8(float4 a, float4 b) {
  union { ushort_t u[8]; uint4 v; } r;
  r.u[0] = f2bf(a.x); r.u[1] = f2bf(a.y); r.u[2] = f2bf(a.z); r.u[3] = f2bf(a.w);
  r.u[4] = f2bf(b.x); r.u[5] = f2bf(b.y); r.u[6] = f2bf(b.z); r.u[7] = f2bf(b.w);
  return r.v;
}

// ---------------- weight GEMM with fused cast+transpose staging + fb (2-in-1):
// blocks 0..15:   Mp2(frag layout) = (wproj @ WvT^T) * gamma, staging straight
//                 from f32 wproj (cast) and f32 wqkv V-block (transpose+cast).
// blocks 16..143: fb[o] = wproj[o,:]·bqkv[1024:1536] + bproj[o]
// Mp2 layout: idx(o,c) = ((((w*8+kb)*2+ks)*4+mi)*64 + q*16+ln)*8 + j
//   w=o>>6, mi=(o>>4)&3, ln=o&15, kb=c>>6, ks=(c>>5)&1, q=(c>>3)&3, j=c&7
__global__ __launch_bounds__(256) void k_wgemm(
    const float* __restrict__ wproj,
    const float* __restrict__ wqkv,
    const float* __restrict__ bqkv,
    const float* __restrict__ bproj,
    const float* __restrict__ gamma,
    ushort_t* __restrict__ Mp2,
    float* __restrict__ fb) {
  int bid = blockIdx.x, tid = threadIdx.x;
  if (bid >= 16) {
    int wave = tid >> 6, lane = tid & 63;
    int o = (bid - 16) * 4 + wave;          // 128 blocks -> o in [0,512)
    float part = 0.f;
#pragma unroll
    for (int i = 0; i < 8; ++i) {
      int k = lane + i * 64;
      part += wproj[o * DIMC + k] * bqkv[1024 + k];
    }
    for (int off = 32; off; off >>= 1) part += __shfl_down(part, off, 64);
    if (lane == 0) fb[o] = part + bproj[o];
    return;
  }

  __shared__ ushort_t As[128 * 64];    // [o-row][64k], (r&7) chunk-XOR
  __shared__ ushort_t Bs[128 * 64];    // [c-row][64k], kkey(c) chunk-XOR
  int c0 = (bid & 3) * 128;
  int o0 = (bid >> 2) * 128;
  int wave = tid >> 6, lane = tid & 63;
  int wo = (wave & 1) * 64, wp = (wave >> 1) * 64;
  int q = lane >> 4, ln = lane & 15;

  f32x4 zero = {0.f, 0.f, 0.f, 0.f};
  f32x4 acc[4][4];
#pragma unroll
  for (int i = 0; i < 4; ++i)
#pragma unroll
    for (int j = 0; j < 4; ++j) acc[i][j] = zero;

  int sr = tid >> 3;                   // A staging: row 0..31 per sweep
  int sc = tid & 7;                    // 16B chunk 0..7
  const float* Ag = wproj + (long)(o0 + sr) * DIMC + sc * 8;
  int kr = tid >> 5;                   // B staging: k-row 0..7 per pass
  int c4 = (tid & 31) * 4;             // 4 c per thread

  for (int kc = 0; kc < DIMC; kc += 64) {
    __syncthreads();
    // A: cast f32 -> bf16, same layout as before
#pragma unroll
    for (int it = 0; it < 4; ++it) {
      int r = sr + it * 32;
      float4 a0 = *(const float4*)(Ag + (long)it * 32 * DIMC + kc);
      float4 a1 = *(const float4*)(Ag + (long)it * 32 * DIMC + kc + 4);
      *(uint4*)(&As[r * 64 + ((sc ^ (r & 7)) * 8)]) = pack8(a0, a1);
    }
    // B: transpose+cast from wqkv V-block rows (coalesced f32 reads along c)
#pragma unroll
    for (int ps = 0; ps < 8; ++ps) {
      int k = kc + ps * 8 + kr;        // global k' in [kc, kc+64)
      float4 b = *(const float4*)(wqkv + (long)(1024 + k) * DIMC + c0 + c4);
      // element (c, klocal): byte = c*128 + ((klocal>>3)^kkey(c))*16 + (klocal&7)*2
      char* bsb = (char*)Bs;
      ushort_t e[4] = {f2bf(b.x), f2bf(b.y), f2bf(b.z), f2bf(b.w)};
#pragma unroll
      for (int i = 0; i < 4; ++i) {
        int c = c4 + i;
        *(ushort_t*)(bsb + c * 128 + ((ps ^ kkey(c)) * 16) + kr * 2) = e[i];
      }
    }
    __syncthreads();
#pragma unroll
    for (int ks = 0; ks < 2; ++ks) {
      int cch = ks * 4 + q;
      short8 af[4], bf[4];
#pragma unroll
      for (int mi = 0; mi < 4; ++mi) {
        int row = wo + mi * 16 + ln;
        af[mi] = *(const short8*)(&As[row * 64 + ((cch ^ (row & 7)) * 8)]);
      }
#pragma unroll
      for (int ni = 0; ni < 4; ++ni) {
        int row = wp + ni * 16 + ln;
        bf[ni] = *(const short8*)(&Bs[row * 64 + ((cch ^ kkey(row)) * 8)]);
      }
#pragma unroll
      for (int mi = 0; mi < 4; ++mi)
#pragma unroll
        for (int ni = 0; ni < 4; ++ni)
          acc[mi][ni] = __builtin_amdgcn_mfma_f32_16x16x32_bf16(af[mi], bf[ni], acc[mi][ni], 0, 0, 0);
    }
  }

#pragma unroll
  for (int mi = 0; mi < 4; ++mi) {
    int obase = o0 + wo + mi * 16 + q * 4;
#pragma unroll
    for (int ni = 0; ni < 4; ++ni) {
      int c = c0 + wp + ni * 16 + ln;
      float g = gamma[c];
      int kb2 = c >> 6, ks2 = (c >> 5) & 1, q2 = (c >> 3) & 3, j2 = c & 7;
#pragma unroll
      for (int r = 0; r < 4; ++r) {
        int o = obase + r;
        int w2 = o >> 6, mi2 = (o >> 4) & 3, ln2 = o & 15;
        long idx = (((((long)w2 * 8 + kb2) * 2 + ks2) * 4 + mi2) * 64 + q2 * 16 + ln2) * 8 + j2;
        Mp2[idx] = f2bf(acc[mi][ni][r] * g);
      }
    }
  }
}

// ---------------- fused transpose + RMS + main GEMM + residual, pipelined.
// Block: 32 p x 512 o, 512 threads = 8 waves (wave w: o in [64w,64w+64), 32 p).
// acc[4][2] = 32 regs/wave -> with launch_bounds(512,6): 3 blocks/CU (24 waves).
// K split into 4 steps of 128 k, double-buffered LDS (2 x 8 KB):
//   step t: issue x-loads for t+1 -> MFMA step t (A direct from frag-layout Mp2,
//   L2-hot; B from LDS) -> cast+transpose-write t+1 -> barrier.
// ss (RMS) accumulated in regs during staging; reduced via shuffles at the end.
__global__ __launch_bounds__(512, 6) void k_fused(
    const float* __restrict__ x,
    const ushort_t* __restrict__ Mp2,  // fragment layout, 512KB (L2-resident)
    const float* __restrict__ fb,
    float* __restrict__ out) {
  __shared__ ushort_t xs[2 * 32 * 128];  // 16 KB: [buf][p(32)][128k swizzled 256B rows]
  __shared__ float red[8 * 32];
  __shared__ float s_sh[32];
  int tid = threadIdx.x;
  long p0 = (long)blockIdx.x * 32;       // grid 1024

  int wave = tid >> 6, lane = tid & 63;
  int q = lane >> 4, ln = lane & 15;

  // staging mapping: 2 k-rows x 4 p per thread per step
  int pi4 = (lane & 7) * 4;              // p 0,4,..,28
  int kq  = tid >> 3;                    // 0..63 -> k-pair kq*2 within step
  const float* xbase = x + p0 + pi4;
  int ch = kq >> 2;                      // 16B chunk 0..15 within 128k row
  int sb = (kq & 3) * 4;                 // byte offset within chunk

  const ushort_t* Aw = Mp2 + (long)wave * 32768 + lane * 8;

  float ss0 = 0.f, ss1 = 0.f, ss2 = 0.f, ss3 = 0.f;
  float4 u0, u1;

#define LOADX(T)                                                   \
  { const float* xp = xbase + (long)((T) * 128 + kq * 2) * PN;     \
    u0 = *(const float4*)(xp);  u1 = *(const float4*)(xp + PN); }

#define SSW(B)                                                                  \
  { ss0 += u0.x * u0.x + u1.x * u1.x;  ss1 += u0.y * u0.y + u1.y * u1.y;        \
    ss2 += u0.z * u0.z + u1.z * u1.z;  ss3 += u0.w * u0.w + u1.w * u1.w;        \
    unsigned int w0 = (unsigned int)f2bf(u0.x) | ((unsigned int)f2bf(u1.x) << 16); \
    unsigned int w1 = (unsigned int)f2bf(u0.y) | ((unsigned int)f2bf(u1.y) << 16); \
    unsigned int w2 = (unsigned int)f2bf(u0.z) | ((unsigned int)f2bf(u1.z) << 16); \
    unsigned int w3 = (unsigned int)f2bf(u0.w) | ((unsigned int)f2bf(u1.w) << 16); \
    char* bb = (char*)xs + (B) * 8192;                                          \
    *(unsigned int*)(bb + (pi4 + 0) * 256 + ((ch ^ kkey(pi4 + 0)) * 16) + sb) = w0; \
    *(unsigned int*)(bb + (pi4 + 1) * 256 + ((ch ^ kkey(pi4 + 1)) * 16) + sb) = w1; \
    *(unsigned int*)(bb + (pi4 + 2) * 256 + ((ch ^ kkey(pi4 + 2)) * 16) + sb) = w2; \
    *(unsigned int*)(bb + (pi4 + 3) * 256 + ((ch ^ kkey(pi4 + 3)) * 16) + sb) = w3; }

  f32x4 zero = {0.f, 0.f, 0.f, 0.f};
  f32x4 acc[4][2];
#pragma unroll
  for (int i = 0; i < 4; ++i)
#pragma unroll
    for (int j = 0; j < 2; ++j) acc[i][j] = zero;

  // prologue: stage step 0
  LOADX(0); SSW(0);
  __syncthreads();

#pragma unroll
  for (int t = 0; t < 4; ++t) {
    if (t < 3) LOADX(t + 1);             // async: in flight under MFMAs
    const char* bb = (const char*)xs + (t & 1) * 8192;
#pragma unroll
    for (int kbl = 0; kbl < 2; ++kbl) {
      int kb = t * 2 + kbl;
#pragma unroll
      for (int ks = 0; ks < 2; ++ks) {
        short8 af[4], bf[2];
#pragma unroll
        for (int mi = 0; mi < 4; ++mi)
          af[mi] = *(const short8*)(Aw + ((kb * 2 + ks) * 4 + mi) * 512);
        int c16 = kbl * 8 + ks * 4 + q;
#pragma unroll
        for (int ni = 0; ni < 2; ++ni) {
          int row = ni * 16 + ln;
          bf[ni] = *(const short8*)(bb + row * 256 + ((c16 ^ kkey(row)) * 16));
        }
#pragma unroll
        for (int mi = 0; mi < 4; ++mi)
#pragma unroll
          for (int ni = 0; ni < 2; ++ni)
            acc[mi][ni] = __builtin_amdgcn_mfma_f32_16x16x32_bf16(af[mi], bf[ni], acc[mi][ni], 0, 0, 0);
      }
    }
    if (t < 3) {
      SSW((t + 1) & 1);
      __syncthreads();
    }
  }

  // ---- RMS reduce: butterfly over the 8 kq-subgroups within each wave
#pragma unroll
  for (int m = 8; m <= 32; m <<= 1) {
    ss0 += __shfl_xor(ss0, m, 64);
    ss1 += __shfl_xor(ss1, m, 64);
    ss2 += __shfl_xor(ss2, m, 64);
    ss3 += __shfl_xor(ss3, m, 64);
  }
  if ((lane & 56) == 0) {                // lanes 0..7
    red[wave * 32 + pi4 + 0] = ss0;
    red[wave * 32 + pi4 + 1] = ss1;
    red[wave * 32 + pi4 + 2] = ss2;
    red[wave * 32 + pi4 + 3] = ss3;
  }
  __syncthreads();
  if (tid < 32) {
    float t = 0.f;
#pragma unroll
    for (int g = 0; g < 8; ++g) t += red[g * 32 + tid];
    s_sh[tid] = SQRTC / fmaxf(sqrtf(t), 1e-12f);
  }
  __syncthreads();

  // ---- epilogue: residual + fused bias + RMS scale (x re-read is L3-hot)
  int wo = wave * 64;
#pragma unroll
  for (int mi = 0; mi < 4; ++mi) {
    int obase = wo + mi * 16 + q * 4;
#pragma unroll
    for (int ni = 0; ni < 2; ++ni) {
      int plocal = ni * 16 + ln;
      long p = p0 + plocal;
      float sv = s_sh[plocal];
#pragma unroll
      for (int r = 0; r < 4; ++r) {
        int o = obase + r;
        out[(long)o * PN + p] = x[(long)o * PN + p] + fb[o] + sv * acc[mi][ni][r];
      }
    }
  }
#undef LOADX
#undef SSW
}

extern "C" void kernel_launch(void* const* d_in, const int* in_sizes, int n_in,
                              void* d_out, int out_size, void* d_ws, size_t ws_size,
                              hipStream_t stream) {
  const float* x     = (const float*)d_in[0];
  const float* gamma = (const float*)d_in[1];
  const float* wqkv  = (const float*)d_in[2];
  const float* bqkv  = (const float*)d_in[3];
  const float* wproj = (const float*)d_in[4];
  const float* bproj = (const float*)d_in[5];

  char* ws = (char*)d_ws;
  ushort_t* Mp2 = (ushort_t*)(ws);             // 512*512 bf16 fragment layout (524288 B)
  float*    fb  = (float*)(ws + 524288);       // 512 f32

  // Mp2(frag) = (wproj @ V-weight^T) * gamma, fb = wproj@bqkv_v + bproj
  k_wgemm<<<dim3(144), dim3(256), 0, stream>>>(wproj, wqkv, bqkv, bproj, gamma, Mp2, fb);
  // out[o][p] = x[o][p] + fb[o] + s[p] * sum_c Mp[o,c]*bf16(x[c,p])
  k_fused<<<dim3(1024), dim3(512), 0, stream>>>(x, Mp2, fb, (float*)d_out);
}

// Round 6
// 188.947 us; speedup vs baseline: 1.1301x; 1.1301x over previous
//
#include <hip/hip_runtime.h>

typedef unsigned short ushort_t;
typedef __attribute__((ext_vector_type(8))) short short8;
typedef __attribute__((ext_vector_type(4))) float f32x4;

#define DIMC 512
#define PN   32768                  // 8*64*64 spatial positions
#define SQRTC 22.627416997969522f   // sqrt(512)

__device__ __forceinline__ ushort_t f2bf(float f) {
  unsigned int u = __float_as_uint(f);
  unsigned int r = u + 0x7fffu + ((u >> 16) & 1u);   // round-to-nearest-even
  return (ushort_t)(r >> 16);
}

// swizzle key: spreads 8 values over 16 consecutive rows AND over stride-4 rows
__device__ __forceinline__ int kkey(int r) { return (r & 7) ^ ((r >> 2) & 7); }

__device__ __forceinline__ uint4 pack8(float4 a, float4 b) {
  union { ushort_t u[8]; uint4 v; } r;
  r.u[0] = f2bf(a.x); r.u[1] = f2bf(a.y); r.u[2] = f2bf(a.z); r.u[3] = f2bf(a.w);
  r.u[4] = f2bf(b.x); r.u[5] = f2bf(b.y); r.u[6] = f2bf(b.z); r.u[7] = f2bf(b.w);
  return r.v;
}

// ---------------- weight GEMM with fused cast+transpose staging + fb (2-in-1):
// blocks 0..15:   Mp2(frag layout) = (wproj @ Wv^T) * gamma, staged straight
//                 from f32 wproj (cast) and f32 wqkv V-block (transpose+cast).
// blocks 16..143: fb[o] = wproj[o,:]·bqkv[1024:1536] + bproj[o]
// Mp2 layout: idx(o,c) = ((((w*8+kb)*2+ks)*4+mi)*64 + q*16+ln)*8 + j
//   w=o>>6, mi=(o>>4)&3, ln=o&15, kb=c>>6, ks=(c>>5)&1, q=(c>>3)&3, j=c&7
__global__ __launch_bounds__(256) void k_wgemm(
    const float* __restrict__ wproj,
    const float* __restrict__ wqkv,
    const float* __restrict__ bqkv,
    const float* __restrict__ bproj,
    const float* __restrict__ gamma,
    ushort_t* __restrict__ Mp2,
    float* __restrict__ fb) {
  int bid = blockIdx.x, tid = threadIdx.x;
  if (bid >= 16) {
    int wave = tid >> 6, lane = tid & 63;
    int o = (bid - 16) * 4 + wave;          // 128 blocks -> o in [0,512)
    float part = 0.f;
#pragma unroll
    for (int i = 0; i < 8; ++i) {
      int k = lane + i * 64;
      part += wproj[o * DIMC + k] * bqkv[1024 + k];
    }
    for (int off = 32; off; off >>= 1) part += __shfl_down(part, off, 64);
    if (lane == 0) fb[o] = part + bproj[o];
    return;
  }

  __shared__ ushort_t As[128 * 64];    // [o-row][64k], (r&7) chunk-XOR
  __shared__ ushort_t Bs[128 * 64];    // [c-row][64k], kkey(c) chunk-XOR
  int c0 = (bid & 3) * 128;
  int o0 = (bid >> 2) * 128;
  int wave = tid >> 6, lane = tid & 63;
  int wo = (wave & 1) * 64, wp = (wave >> 1) * 64;
  int q = lane >> 4, ln = lane & 15;

  f32x4 zero = {0.f, 0.f, 0.f, 0.f};
  f32x4 acc[4][4];
#pragma unroll
  for (int i = 0; i < 4; ++i)
#pragma unroll
    for (int j = 0; j < 4; ++j) acc[i][j] = zero;

  int sr = tid >> 3;                   // A staging: row 0..31 per sweep
  int sc = tid & 7;                    // 16B chunk 0..7
  const float* Ag = wproj + (long)(o0 + sr) * DIMC + sc * 8;
  int kr = tid >> 5;                   // B staging: k-row 0..7 per pass
  int c4 = (tid & 31) * 4;             // 4 c per thread

  for (int kc = 0; kc < DIMC; kc += 64) {
    __syncthreads();
    // A: cast f32 -> bf16
#pragma unroll
    for (int it = 0; it < 4; ++it) {
      int r = sr + it * 32;
      float4 a0 = *(const float4*)(Ag + (long)it * 32 * DIMC + kc);
      float4 a1 = *(const float4*)(Ag + (long)it * 32 * DIMC + kc + 4);
      *(uint4*)(&As[r * 64 + ((sc ^ (r & 7)) * 8)]) = pack8(a0, a1);
    }
    // B: transpose+cast from wqkv V-block rows (coalesced f32 reads along c)
#pragma unroll
    for (int ps = 0; ps < 8; ++ps) {
      int k = kc + ps * 8 + kr;        // global k' in [kc, kc+64)
      float4 b = *(const float4*)(wqkv + (long)(1024 + k) * DIMC + c0 + c4);
      char* bsb = (char*)Bs;
      ushort_t e[4] = {f2bf(b.x), f2bf(b.y), f2bf(b.z), f2bf(b.w)};
#pragma unroll
      for (int i = 0; i < 4; ++i) {
        int c = c4 + i;
        *(ushort_t*)(bsb + c * 128 + ((ps ^ kkey(c)) * 16) + kr * 2) = e[i];
      }
    }
    __syncthreads();
#pragma unroll
    for (int ks = 0; ks < 2; ++ks) {
      int cch = ks * 4 + q;
      short8 af[4], bf[4];
#pragma unroll
      for (int mi = 0; mi < 4; ++mi) {
        int row = wo + mi * 16 + ln;
        af[mi] = *(const short8*)(&As[row * 64 + ((cch ^ (row & 7)) * 8)]);
      }
#pragma unroll
      for (int ni = 0; ni < 4; ++ni) {
        int row = wp + ni * 16 + ln;
        bf[ni] = *(const short8*)(&Bs[row * 64 + ((cch ^ kkey(row)) * 8)]);
      }
#pragma unroll
      for (int mi = 0; mi < 4; ++mi)
#pragma unroll
        for (int ni = 0; ni < 4; ++ni)
          acc[mi][ni] = __builtin_amdgcn_mfma_f32_16x16x32_bf16(af[mi], bf[ni], acc[mi][ni], 0, 0, 0);
    }
  }

#pragma unroll
  for (int mi = 0; mi < 4; ++mi) {
    int obase = o0 + wo + mi * 16 + q * 4;
#pragma unroll
    for (int ni = 0; ni < 4; ++ni) {
      int c = c0 + wp + ni * 16 + ln;
      float g = gamma[c];
      int kb2 = c >> 6, ks2 = (c >> 5) & 1, q2 = (c >> 3) & 3, j2 = c & 7;
#pragma unroll
      for (int r = 0; r < 4; ++r) {
        int o = obase + r;
        int w2 = o >> 6, mi2 = (o >> 4) & 3, ln2 = o & 15;
        long idx = (((((long)w2 * 8 + kb2) * 2 + ks2) * 4 + mi2) * 64 + q2 * 16 + ln2) * 8 + j2;
        Mp2[idx] = f2bf(acc[mi][ni][r] * g);
      }
    }
  }
}

// ---------------- fused transpose + RMS + main GEMM + residual, kb-pipelined.
// Round-4 geometry (proven 56us): block = 64 p x 512 o, 512 thr = 8 waves,
// wave w: o in [64w,64w+64), all 64 p; acc[4][4]; 2 blocks/CU (LDS-capped).
// NEW: staging split into 8 per-kb chunks (8 KB each), pipelined:
//   prologue stage kb0; loop kb: issue x-loads kb+1 -> 32 MFMAs on kb
//   (A direct from L2-hot frag-layout Mp2) -> cast+write kb+1 -> barrier.
// HBM staging latency hides under MFMA + 16-wave TLP (T14 issue-early).
__global__ __launch_bounds__(512, 4) void k_fused(
    const float* __restrict__ x,
    const ushort_t* __restrict__ Mp2,  // fragment layout, 512KB (L2-resident)
    const float* __restrict__ fb,
    float* __restrict__ out) {
  __shared__ ushort_t xs[8 * 64 * 64];   // 64 KB: 8 kb-buffers [p(64)][64k swizzled]
  __shared__ float red[32 * 65];
  __shared__ float s_sh[64];
  int tid = threadIdx.x;
  long p0 = (long)blockIdx.x * 64;       // grid 512

  int wave = tid >> 6, lane = tid & 63;
  int q = lane >> 4, ln = lane & 15;

  // staging mapping: per kb each thread stages 2 k-rows x 4 p
  int pl4 = (tid & 15) * 4;              // p-group base 0,4,..,60
  int kp  = tid >> 4;                    // 0..31 k-pair index
  int kl  = kp * 2;                      // even local k
  int ch  = kl >> 3;                     // 16B chunk 0..7
  int sub = (kl & 7) * 2;                // byte offset in chunk: 0,4,8,12
  const float* xb = x + p0 + pl4;

  const ushort_t* Aw = Mp2 + (long)wave * 32768 + lane * 8;

  float ss0 = 0.f, ss1 = 0.f, ss2 = 0.f, ss3 = 0.f;
  float4 u0, u1;

#define LOADX(KB)                                                  \
  { const float* xp = xb + (long)((KB) * 64 + kl) * PN;            \
    u0 = *(const float4*)(xp);  u1 = *(const float4*)(xp + PN); }

#define SSW(KB)                                                                 \
  { ss0 += u0.x * u0.x + u1.x * u1.x;  ss1 += u0.y * u0.y + u1.y * u1.y;        \
    ss2 += u0.z * u0.z + u1.z * u1.z;  ss3 += u0.w * u0.w + u1.w * u1.w;        \
    unsigned int w0 = (unsigned int)f2bf(u0.x) | ((unsigned int)f2bf(u1.x) << 16); \
    unsigned int w1 = (unsigned int)f2bf(u0.y) | ((unsigned int)f2bf(u1.y) << 16); \
    unsigned int w2 = (unsigned int)f2bf(u0.z) | ((unsigned int)f2bf(u1.z) << 16); \
    unsigned int w3 = (unsigned int)f2bf(u0.w) | ((unsigned int)f2bf(u1.w) << 16); \
    char* bb = (char*)xs + (KB) * 8192;                                         \
    *(unsigned int*)(bb + (pl4 + 0) * 128 + ((ch ^ kkey(pl4 + 0)) * 16) + sub) = w0; \
    *(unsigned int*)(bb + (pl4 + 1) * 128 + ((ch ^ kkey(pl4 + 1)) * 16) + sub) = w1; \
    *(unsigned int*)(bb + (pl4 + 2) * 128 + ((ch ^ kkey(pl4 + 2)) * 16) + sub) = w2; \
    *(unsigned int*)(bb + (pl4 + 3) * 128 + ((ch ^ kkey(pl4 + 3)) * 16) + sub) = w3; }

  f32x4 zero = {0.f, 0.f, 0.f, 0.f};
  f32x4 acc[4][4];
#pragma unroll
  for (int i = 0; i < 4; ++i)
#pragma unroll
    for (int j = 0; j < 4; ++j) acc[i][j] = zero;

  // prologue: stage kb=0
  LOADX(0); SSW(0);
  __syncthreads();

#pragma unroll
  for (int kb = 0; kb < 8; ++kb) {
    if (kb < 7) LOADX(kb + 1);           // issue next-chunk loads under MFMAs
    const char* bbase = (const char*)xs + kb * 8192;
#pragma unroll
    for (int ks = 0; ks < 2; ++ks) {
      short8 af[4], bf[4];
#pragma unroll
      for (int mi = 0; mi < 4; ++mi)
        af[mi] = *(const short8*)(Aw + ((kb * 2 + ks) * 4 + mi) * 512);
      int cch = ks * 4 + q;
#pragma unroll
      for (int ni = 0; ni < 4; ++ni) {
        int row = ni * 16 + ln;
        bf[ni] = *(const short8*)(bbase + row * 128 + ((cch ^ kkey(row)) * 16));
      }
#pragma unroll
      for (int mi = 0; mi < 4; ++mi)
#pragma unroll
        for (int ni = 0; ni < 4; ++ni)
          acc[mi][ni] = __builtin_amdgcn_mfma_f32_16x16x32_bf16(af[mi], bf[ni], acc[mi][ni], 0, 0, 0);
    }
    if (kb < 7) {
      SSW(kb + 1);                       // write-late: vmcnt waits land here
      __syncthreads();                   // publish kb+1
    }
  }

  // ---- RMS reduce: red[kp][p] partials (each thread covered 16 k-rows x 4 p)
  red[kp * 65 + pl4 + 0] = ss0;
  red[kp * 65 + pl4 + 1] = ss1;
  red[kp * 65 + pl4 + 2] = ss2;
  red[kp * 65 + pl4 + 3] = ss3;
  __syncthreads();
  if (tid < 64) {
    float t = 0.f;
#pragma unroll
    for (int g = 0; g < 32; ++g) t += red[g * 65 + tid];
    s_sh[tid] = SQRTC / fmaxf(sqrtf(t), 1e-12f);
  }
  __syncthreads();

  // ---- epilogue: residual + fused bias + RMS scale (x re-read is L2/L3-hot)
  int wo = wave * 64;
#pragma unroll
  for (int mi = 0; mi < 4; ++mi) {
    int obase = wo + mi * 16 + q * 4;
#pragma unroll
    for (int ni = 0; ni < 4; ++ni) {
      int plocal = ni * 16 + ln;
      long p = p0 + plocal;
      float sv = s_sh[plocal];
#pragma unroll
      for (int r = 0; r < 4; ++r) {
        int o = obase + r;
        out[(long)o * PN + p] = x[(long)o * PN + p] + fb[o] + sv * acc[mi][ni][r];
      }
    }
  }
#undef LOADX
#undef SSW
}

extern "C" void kernel_launch(void* const* d_in, const int* in_sizes, int n_in,
                              void* d_out, int out_size, void* d_ws, size_t ws_size,
                              hipStream_t stream) {
  const float* x     = (const float*)d_in[0];
  const float* gamma = (const float*)d_in[1];
  const float* wqkv  = (const float*)d_in[2];
  const float* bqkv  = (const float*)d_in[3];
  const float* wproj = (const float*)d_in[4];
  const float* bproj = (const float*)d_in[5];

  char* ws = (char*)d_ws;
  ushort_t* Mp2 = (ushort_t*)(ws);             // 512*512 bf16 fragment layout (524288 B)
  float*    fb  = (float*)(ws + 524288);       // 512 f32

  // Mp2(frag) = (wproj @ V-weight^T) * gamma, fb = wproj@bqkv_v + bproj
  k_wgemm<<<dim3(144), dim3(256), 0, stream>>>(wproj, wqkv, bqkv, bproj, gamma, Mp2, fb);
  // out[o][p] = x[o][p] + fb[o] + s[p] * sum_c Mp[o,c]*bf16(x[c,p])
  k_fused<<<dim3(512), dim3(512), 0, stream>>>(x, Mp2, fb, (float*)d_out);
}

// Round 8
// 171.428 us; speedup vs baseline: 1.2456x; 1.1022x over previous
//
#include <hip/hip_runtime.h>

typedef unsigned short ushort_t;
typedef __attribute__((ext_vector_type(8))) short short8;
typedef __attribute__((ext_vector_type(4))) float f32x4;

#define DIMC 512
#define PN   32768                  // 8*64*64 spatial positions
#define SQRTC 22.627416997969522f   // sqrt(512)

__device__ __forceinline__ ushort_t f2bf(float f) {
  unsigned int u = __float_as_uint(f);
  unsigned int r = u + 0x7fffu + ((u >> 16) & 1u);   // round-to-nearest-even
  return (ushort_t)(r >> 16);
}

// swizzle key: spreads 8 values over 16 consecutive rows AND over stride-4 rows
__device__ __forceinline__ int kkey(int r) { return (r & 7) ^ ((r >> 2) & 7); }

__device__ __forceinline__ uint4 pack8(float4 a, float4 b) {
  union { ushort_t u[8]; uint4 v; } r;
  r.u[0] = f2bf(a.x); r.u[1] = f2bf(a.y); r.u[2] = f2bf(a.z); r.u[3] = f2bf(a.w);
  r.u[4] = f2bf(b.x); r.u[5] = f2bf(b.y); r.u[6] = f2bf(b.z); r.u[7] = f2bf(b.w);
  return r.v;
}

// ---------------- weight GEMM with fused cast+transpose staging + fb (2-in-1):
// blocks 0..15:   Mp2(frag layout) = (wproj @ Wv^T) * gamma
// blocks 16..143: fb[o] = wproj[o,:]·bqkv[1024:1536] + bproj[o]
// Mp2 layout: idx(o,c) = ((((w*8+kb)*2+ks)*4+mi)*64 + q*16+ln)*8 + j
//   w=o>>6, mi=(o>>4)&3, ln=o&15, kb=c>>6, ks=(c>>5)&1, q=(c>>3)&3, j=c&7
__global__ __launch_bounds__(256) void k_wgemm(
    const float* __restrict__ wproj,
    const float* __restrict__ wqkv,
    const float* __restrict__ bqkv,
    const float* __restrict__ bproj,
    const float* __restrict__ gamma,
    ushort_t* __restrict__ Mp2,
    float* __restrict__ fb) {
  int bid = blockIdx.x, tid = threadIdx.x;
  if (bid >= 16) {
    int wave = tid >> 6, lane = tid & 63;
    int o = (bid - 16) * 4 + wave;          // 128 blocks -> o in [0,512)
    float part = 0.f;
#pragma unroll
    for (int i = 0; i < 8; ++i) {
      int k = lane + i * 64;
      part += wproj[o * DIMC + k] * bqkv[1024 + k];
    }
    for (int off = 32; off; off >>= 1) part += __shfl_down(part, off, 64);
    if (lane == 0) fb[o] = part + bproj[o];
    return;
  }

  __shared__ ushort_t As[128 * 64];    // [o-row][64k], (r&7) chunk-XOR
  __shared__ ushort_t Bs[128 * 64];    // [c-row][64k], kkey(c) chunk-XOR
  int c0 = (bid & 3) * 128;
  int o0 = (bid >> 2) * 128;
  int wave = tid >> 6, lane = tid & 63;
  int wo = (wave & 1) * 64, wp = (wave >> 1) * 64;
  int q = lane >> 4, ln = lane & 15;

  f32x4 zero = {0.f, 0.f, 0.f, 0.f};
  f32x4 acc[4][4];
#pragma unroll
  for (int i = 0; i < 4; ++i)
#pragma unroll
    for (int j = 0; j < 4; ++j) acc[i][j] = zero;

  int sr = tid >> 3;                   // A staging: row 0..31 per sweep
  int sc = tid & 7;                    // 16B chunk 0..7
  const float* Ag = wproj + (long)(o0 + sr) * DIMC + sc * 8;
  int kr = tid >> 5;                   // B staging: k-row 0..7 per pass
  int c4 = (tid & 31) * 4;             // 4 c per thread

  for (int kc = 0; kc < DIMC; kc += 64) {
    __syncthreads();
    // A: cast f32 -> bf16
#pragma unroll
    for (int it = 0; it < 4; ++it) {
      int r = sr + it * 32;
      float4 a0 = *(const float4*)(Ag + (long)it * 32 * DIMC + kc);
      float4 a1 = *(const float4*)(Ag + (long)it * 32 * DIMC + kc + 4);
      *(uint4*)(&As[r * 64 + ((sc ^ (r & 7)) * 8)]) = pack8(a0, a1);
    }
    // B: transpose+cast from wqkv V-block rows (coalesced f32 reads along c)
#pragma unroll
    for (int ps = 0; ps < 8; ++ps) {
      int k = kc + ps * 8 + kr;        // global k' in [kc, kc+64)
      float4 b = *(const float4*)(wqkv + (long)(1024 + k) * DIMC + c0 + c4);
      char* bsb = (char*)Bs;
      ushort_t e[4] = {f2bf(b.x), f2bf(b.y), f2bf(b.z), f2bf(b.w)};
#pragma unroll
      for (int i = 0; i < 4; ++i) {
        int c = c4 + i;
        *(ushort_t*)(bsb + c * 128 + ((ps ^ kkey(c)) * 16) + kr * 2) = e[i];
      }
    }
    __syncthreads();
#pragma unroll
    for (int ks = 0; ks < 2; ++ks) {
      int cch = ks * 4 + q;
      short8 af[4], bf[4];
#pragma unroll
      for (int mi = 0; mi < 4; ++mi) {
        int row = wo + mi * 16 + ln;
        af[mi] = *(const short8*)(&As[row * 64 + ((cch ^ (row & 7)) * 8)]);
      }
#pragma unroll
      for (int ni = 0; ni < 4; ++ni) {
        int row = wp + ni * 16 + ln;
        bf[ni] = *(const short8*)(&Bs[row * 64 + ((cch ^ kkey(row)) * 8)]);
      }
#pragma unroll
      for (int mi = 0; mi < 4; ++mi)
#pragma unroll
        for (int ni = 0; ni < 4; ++ni)
          acc[mi][ni] = __builtin_amdgcn_mfma_f32_16x16x32_bf16(af[mi], bf[ni], acc[mi][ni], 0, 0, 0);
    }
  }

#pragma unroll
  for (int mi = 0; mi < 4; ++mi) {
    int obase = o0 + wo + mi * 16 + q * 4;
#pragma unroll
    for (int ni = 0; ni < 4; ++ni) {
      int c = c0 + wp + ni * 16 + ln;
      float g = gamma[c];
      int kb2 = c >> 6, ks2 = (c >> 5) & 1, q2 = (c >> 3) & 3, j2 = c & 7;
#pragma unroll
      for (int r = 0; r < 4; ++r) {
        int o = obase + r;
        int w2 = o >> 6, mi2 = (o >> 4) & 3, ln2 = o & 15;
        long idx = (((((long)w2 * 8 + kb2) * 2 + ks2) * 4 + mi2) * 64 + q2 * 16 + ln2) * 8 + j2;
        Mp2[idx] = f2bf(acc[mi][ni][r] * g);
      }
    }
  }
}

// ---------------- fused transpose + RMS + main GEMM + residual, ILP version.
// Round-4 geometry (proven): block = 64 p x 512 o, 8 waves, acc[4][4].
// launch_bounds(512,2): 256-reg budget, 1 block/CU -> compiler gets headroom:
//   - staging issues ALL 16 float4 x-loads before processing (deep MLP)
//   - A-fragments ping-pong prefetched one kb ahead (L2-hot, coalesced)
//   - s-reduction runs on wave 0 concurrently with other waves' GEMM
__global__ __launch_bounds__(512, 2) void k_fused(
    const float* __restrict__ x,
    const ushort_t* __restrict__ Mp2,  // fragment layout, 512KB (L2-resident)
    const float* __restrict__ fb,
    float* __restrict__ out) {
  __shared__ ushort_t xs[8 * 64 * 64];   // 64 KB: 8 kb-buffers [p(64)][64k swizzled]
  __shared__ float red[32 * 65];
  __shared__ float s_sh[64];
  int tid = threadIdx.x;
  long p0 = (long)blockIdx.x * 64;       // grid 512

  int wave = tid >> 6, lane = tid & 63;
  int q = lane >> 4, ln = lane & 15;

  const ushort_t* Aw = Mp2 + (long)wave * 32768 + lane * 8;

  // ---- staging: issue all 16 float4 loads (batched MLP), then process
  int pl4 = (tid & 15) * 4;              // p-group base 0,4,..,60
  int kq  = tid >> 4;                    // 0..31
  float4 v[16];
#pragma unroll
  for (int sw = 0; sw < 4; ++sw) {
    const float* xp = x + (long)(kq * 4 + sw * 128) * PN + p0 + pl4;
#pragma unroll
    for (int j = 0; j < 4; ++j)
      v[sw * 4 + j] = *(const float4*)(xp + (long)j * PN);
  }

  // A-fragments for kb=0 issued while x-loads are in flight / being processed
  short8 afb[2][8];
#pragma unroll
  for (int f = 0; f < 8; ++f) afb[0][f] = *(const short8*)(Aw + f * 512);

  float ss0 = 0.f, ss1 = 0.f, ss2 = 0.f, ss3 = 0.f;
#pragma unroll
  for (int sw = 0; sw < 4; ++sw) {
    int k4 = kq * 4 + sw * 128;
    float4 v0 = v[sw * 4 + 0], v1 = v[sw * 4 + 1];
    float4 v2 = v[sw * 4 + 2], v3 = v[sw * 4 + 3];
    ss0 += v0.x * v0.x + v1.x * v1.x + v2.x * v2.x + v3.x * v3.x;
    ss1 += v0.y * v0.y + v1.y * v1.y + v2.y * v2.y + v3.y * v3.y;
    ss2 += v0.z * v0.z + v1.z * v1.z + v2.z * v2.z + v3.z * v3.z;
    ss3 += v0.w * v0.w + v1.w * v1.w + v2.w * v2.w + v3.w * v3.w;
    ushort_t t0[4] = {f2bf(v0.x), f2bf(v1.x), f2bf(v2.x), f2bf(v3.x)};
    ushort_t t1[4] = {f2bf(v0.y), f2bf(v1.y), f2bf(v2.y), f2bf(v3.y)};
    ushort_t t2[4] = {f2bf(v0.z), f2bf(v1.z), f2bf(v2.z), f2bf(v3.z)};
    ushort_t t3[4] = {f2bf(v0.w), f2bf(v1.w), f2bf(v2.w), f2bf(v3.w)};
    char* base = (char*)xs + (k4 >> 6) * 8192;
    int ch  = (k4 >> 3) & 7;             // 16B chunk within 64-k row
    int sub = (k4 & 7) * 2;              // byte offset within chunk (0 or 8)
    *(uint2*)(base + (pl4 + 0) * 128 + ((ch ^ kkey(pl4 + 0)) * 16) + sub) = *(const uint2*)t0;
    *(uint2*)(base + (pl4 + 1) * 128 + ((ch ^ kkey(pl4 + 1)) * 16) + sub) = *(const uint2*)t1;
    *(uint2*)(base + (pl4 + 2) * 128 + ((ch ^ kkey(pl4 + 2)) * 16) + sub) = *(const uint2*)t2;
    *(uint2*)(base + (pl4 + 3) * 128 + ((ch ^ kkey(pl4 + 3)) * 16) + sub) = *(const uint2*)t3;
  }
  red[kq * 65 + pl4 + 0] = ss0;
  red[kq * 65 + pl4 + 1] = ss1;
  red[kq * 65 + pl4 + 2] = ss2;
  red[kq * 65 + pl4 + 3] = ss3;
  __syncthreads();                       // publish xs + red

  // ---- wave 0 reduces s while all waves (incl. 0, after) run the GEMM
  if (tid < 64) {
    float t = 0.f;
#pragma unroll
    for (int g = 0; g < 32; ++g) t += red[g * 65 + tid];
    s_sh[tid] = SQRTC / fmaxf(sqrtf(t), 1e-12f);
  }

  // ---- barrier-free GEMM: wave w owns o in [64w, 64w+64), all 64 p
  f32x4 zero = {0.f, 0.f, 0.f, 0.f};
  f32x4 acc[4][4];
#pragma unroll
  for (int i = 0; i < 4; ++i)
#pragma unroll
    for (int j = 0; j < 4; ++j) acc[i][j] = zero;

#pragma unroll
  for (int kb = 0; kb < 8; ++kb) {
    // prefetch next kb's A-fragments (coalesced 1KB L2 loads) under the MFMAs
    if (kb < 7) {
#pragma unroll
      for (int f = 0; f < 8; ++f)
        afb[(kb + 1) & 1][f] = *(const short8*)(Aw + ((kb + 1) * 8 + f) * 512);
    }
    const char* bbase = (const char*)xs + kb * 8192;
#pragma unroll
    for (int ks = 0; ks < 2; ++ks) {
      int cch = ks * 4 + q;
      short8 bf[4];
#pragma unroll
      for (int ni = 0; ni < 4; ++ni) {
        int row = ni * 16 + ln;
        bf[ni] = *(const short8*)(bbase + row * 128 + ((cch ^ kkey(row)) * 16));
      }
#pragma unroll
      for (int mi = 0; mi < 4; ++mi)
#pragma unroll
        for (int ni = 0; ni < 4; ++ni)
          acc[mi][ni] = __builtin_amdgcn_mfma_f32_16x16x32_bf16(
              afb[kb & 1][ks * 4 + mi], bf[ni], acc[mi][ni], 0, 0, 0);
    }
  }
  __syncthreads();                       // s_sh visible to all

  // ---- epilogue: residual + fused bias + RMS scale (x re-read is L2/L3-hot)
  int wo = wave * 64;
#pragma unroll
  for (int mi = 0; mi < 4; ++mi) {
    int obase = wo + mi * 16 + q * 4;
#pragma unroll
    for (int ni = 0; ni < 4; ++ni) {
      int plocal = ni * 16 + ln;
      long p = p0 + plocal;
      float sv = s_sh[plocal];
#pragma unroll
      for (int r = 0; r < 4; ++r) {
        int o = obase + r;
        out[(long)o * PN + p] = x[(long)o * PN + p] + fb[o] + sv * acc[mi][ni][r];
      }
    }
  }
}

extern "C" void kernel_launch(void* const* d_in, const int* in_sizes, int n_in,
                              void* d_out, int out_size, void* d_ws, size_t ws_size,
                              hipStream_t stream) {
  const float* x     = (const float*)d_in[0];
  const float* gamma = (const float*)d_in[1];
  const float* wqkv  = (const float*)d_in[2];
  const float* bqkv  = (const float*)d_in[3];
  const float* wproj = (const float*)d_in[4];
  const float* bproj = (const float*)d_in[5];

  char* ws = (char*)d_ws;
  ushort_t* Mp2 = (ushort_t*)(ws);             // 512*512 bf16 fragment layout (524288 B)
  float*    fb  = (float*)(ws + 524288);       // 512 f32

  // Mp2(frag) = (wproj @ V-weight^T) * gamma, fb = wproj@bqkv_v + bproj
  k_wgemm<<<dim3(144), dim3(256), 0, stream>>>(wproj, wqkv, bqkv, bproj, gamma, Mp2, fb);
  // out[o][p] = x[o][p] + fb[o] + s[p] * sum_c Mp[o,c]*bf16(x[c,p])
  k_fused<<<dim3(512), dim3(512), 0, stream>>>(x, Mp2, fb, (float*)d_out);
}